// Round 9
// baseline (81.835 us; speedup 1.0000x reference)
//
#include <hip/hip_runtime.h>
#include <hip/hip_bf16.h>
#include <math.h>

#define BB 64
#define NN 64
#define HH 256
#define FF 8

typedef __bf16 bf16;
typedef bf16 bf16x2 __attribute__((ext_vector_type(2)));
typedef bf16 bf16x4 __attribute__((ext_vector_type(4)));
typedef bf16 bf16x8 __attribute__((ext_vector_type(8)));
typedef float f32x2 __attribute__((ext_vector_type(2)));
typedef float f32x4 __attribute__((ext_vector_type(4)));

// async global->LDS, 16B per lane; LDS dest = uniform base + lane*16,
// global src must be PER-LANE (carry the lane offset explicitly!)
#define GLL(g, l) __builtin_amdgcn_global_load_lds( \
    (const __attribute__((address_space(1))) void*)(g), \
    (__attribute__((address_space(3))) void*)(l), 16, 0, 0)

#define MFMA(a, b, c) __builtin_amdgcn_mfma_f32_16x16x32_bf16(a, b, c, 0, 0, 0)

__device__ __forceinline__ f32x2 unpk(unsigned int u) {
    union { unsigned int i; float f; } a, b;
    a.i = (u & 0xffffu) << 16;
    b.i = u & 0xffff0000u;
    f32x2 r; r.x = a.f; r.y = b.f; return r;
}

// fragment from swizzled LDS tile with 128-B rows
__device__ __forceinline__ bf16x8 frag128(const char* base, int row, int cbyte) {
    const int sw = (row & 7) << 4;
    const int a = row * 128 + cbyte;
    bf16x4 lo = *(const bf16x4*)(base + (a ^ sw));
    bf16x4 hi = *(const bf16x4*)(base + ((a + 32) ^ sw));
    return __builtin_shufflevector(lo, hi, 0, 1, 2, 3, 4, 5, 6, 7);
}

// fragment from swizzled LDS tile with 512-B rows (64 rows x 256 k bf16)
__device__ __forceinline__ bf16x8 frag512(const char* base, int row, int cbyte) {
    const int sw = (row & 7) << 4;
    const int a = row * 512 + cbyte;
    bf16x4 lo = *(const bf16x4*)(base + (a ^ sw));
    bf16x4 hi = *(const bf16x4*)(base + ((a + 32) ^ sw));
    return __builtin_shufflevector(lo, hi, 0, 1, 2, 3, 4, 5, 6, 7);
}

// ---------------------------------------------------------------------------
// G1 + pack, one dispatch. Grid (16, 71):
//   y in [0,64): G1 tile (bm=y*64, bn=x*64): PQ = bf16(hidden @ [W1top|W1bot])
//     - B staged in-kernel from fp32 ed_w1 via LDS transpose (4-step prologue
//       into resident swizzled Bs[64][256]); A staged fp32->bf16 per k-step.
//   y in [64,71): pack blocks t=(y-64)*16+x in [0,112):
//     t<32: ed_w2 -> W2t [256][512]; else wr,wi,wh,f1_w,f2_w -> Wg/f1t/f2t.
// ---------------------------------------------------------------------------
__global__ __launch_bounds__(256) void g1pack_kernel(
    const float* __restrict__ hidden, const float* __restrict__ ed_w1,
    const float* __restrict__ ed_w2,
    const float* __restrict__ wr, const float* __restrict__ wi,
    const float* __restrict__ wh,
    const float* __restrict__ f1_w, const float* __restrict__ f2_w,
    bf16* __restrict__ PQ, bf16* __restrict__ W2t, bf16* __restrict__ Wg,
    bf16* __restrict__ f1t, bf16* __restrict__ f2t)
{
    __shared__ __align__(1024) char smem[49408];
    const int tid = threadIdx.x;

    if (blockIdx.y >= 64) {
        // ---- pack branch ----
        const int t = (blockIdx.y - 64) * 16 + blockIdx.x;
        const float* src; bf16* dst; int R, C, tile;
        if (t < 32) { src = ed_w2; dst = W2t; R = 512; C = 256; tile = t; }
        else {
            int m = (t - 32) >> 4; tile = (t - 32) & 15; R = 256; C = 256;
            const float* ss[5] = {wr, wi, wh, f1_w, f2_w};
            bf16* dd[5] = {Wg, Wg + 65536, Wg + 131072, f1t, f2t};
            src = ss[m]; dst = dd[m];
        }
        const int tc = C >> 6;
        const int k0 = (tile / tc) * 64, n0 = (tile % tc) * 64;
        float (*ls)[65] = (float(*)[65])smem;
        {
            int rr = tid >> 2, cc = (tid & 3) * 16;
            const float* sp = src + (size_t)(k0 + rr) * C + n0 + cc;
#pragma unroll
            for (int j = 0; j < 16; j += 4) {
                float4 v = *(const float4*)(sp + j);
                ls[rr][cc + j] = v.x; ls[rr][cc + j + 1] = v.y;
                ls[rr][cc + j + 2] = v.z; ls[rr][cc + j + 3] = v.w;
            }
        }
        __syncthreads();
        {
            int n = tid >> 2, kc = (tid & 3) * 16;
            bf16x8 o0, o1;
#pragma unroll
            for (int j = 0; j < 8; ++j) o0[j] = (bf16)ls[kc + j][n];
#pragma unroll
            for (int j = 0; j < 8; ++j) o1[j] = (bf16)ls[kc + 8 + j][n];
            bf16* dp = dst + (size_t)(n0 + n) * R + k0 + kc;
            *(bf16x8*)dp = o0;
            *(bf16x8*)(dp + 8) = o1;
        }
        return;
    }

    // ---- G1 branch ----
    char* Bs = smem;               // [64][256] bf16 swizzled, 32 KB, resident
    char* pool = smem + 32768;     // 16640 B: ls (prologue) / A dbuf (main)
    const int wave = tid >> 6, lane = tid & 63;
    const int wr_ = wave >> 1, wc_ = wave & 1;
    const int l15 = lane & 15, l4 = lane >> 4;
    const int bm = blockIdx.y * 64, bn = blockIdx.x * 64;
    const int roff = (bn >= 512) ? 256 : 0;   // W1t[n][k]=ed_w1[n<512?k:k+256][n&511]
    const int ncol = bn & 511;

    // prologue: B = transpose+cvt of ed_w1 block into swizzled Bs
    {
        float (*ls)[65] = (float(*)[65])pool;
#pragma unroll
        for (int kt = 0; kt < 4; ++kt) {
            {
                int rr = tid >> 2, cc = (tid & 3) * 16;
                const float* sp = ed_w1 + (size_t)(kt * 64 + roff + rr) * 512 + ncol + cc;
#pragma unroll
                for (int j = 0; j < 16; j += 4) {
                    float4 v = *(const float4*)(sp + j);
                    ls[rr][cc + j] = v.x; ls[rr][cc + j + 1] = v.y;
                    ls[rr][cc + j + 2] = v.z; ls[rr][cc + j + 3] = v.w;
                }
            }
            __syncthreads();
            {
                int n = tid >> 2, kc = (tid & 3) * 16;
                bf16x8 o0, o1;
#pragma unroll
                for (int j = 0; j < 8; ++j) o0[j] = (bf16)ls[kc + j][n];
#pragma unroll
                for (int j = 0; j < 8; ++j) o1[j] = (bf16)ls[kc + 8 + j][n];
                int cb0 = kt * 8 + (kc >> 3);
                char* rowp = Bs + n * 512;
                *(bf16x8*)(rowp + ((cb0 ^ (n & 7)) * 16)) = o0;
                *(bf16x8*)(rowp + (((cb0 + 1) ^ (n & 7)) * 16)) = o1;
            }
            __syncthreads();
        }
    }

    f32x4 acc[2][2];
#pragma unroll
    for (int mf = 0; mf < 2; ++mf)
#pragma unroll
        for (int nf = 0; nf < 2; ++nf)
            acc[mf][nf] = (f32x4){0.f, 0.f, 0.f, 0.f};

    auto stageA = [&](int buf, int kt) {
        char* Ab = pool + buf * 8192;
#pragma unroll
        for (int a = 0; a < 2; ++a) {
            int idx = a * 256 + tid;
            int row = idx >> 3, cb = idx & 7;
            const float* gp = hidden + (size_t)(bm + row) * 256 + kt * 64 + cb * 8;
            float4 v0 = *(const float4*)gp;
            float4 v1 = *(const float4*)(gp + 4);
            bf16x8 o;
            o[0] = (bf16)v0.x; o[1] = (bf16)v0.y; o[2] = (bf16)v0.z; o[3] = (bf16)v0.w;
            o[4] = (bf16)v1.x; o[5] = (bf16)v1.y; o[6] = (bf16)v1.z; o[7] = (bf16)v1.w;
            *(bf16x8*)(Ab + row * 128 + ((cb ^ (row & 7)) * 16)) = o;
        }
    };

    auto computeT = [&](int buf, int kt) {
        char* Ab = pool + buf * 8192;
#pragma unroll
        for (int kk = 0; kk < 2; ++kk) {
            bf16x8 af[2];
#pragma unroll
            for (int mf = 0; mf < 2; ++mf)
                af[mf] = frag128(Ab, wr_ * 32 + mf * 16 + l15, kk * 64 + l4 * 8);
#pragma unroll
            for (int nf = 0; nf < 2; ++nf) {
                bf16x8 bfr = frag512(Bs, wc_ * 32 + nf * 16 + l15,
                                     kt * 128 + kk * 64 + l4 * 8);
#pragma unroll
                for (int mf = 0; mf < 2; ++mf)
                    acc[mf][nf] = MFMA(af[mf], bfr, acc[mf][nf]);
            }
        }
    };

    stageA(0, 0);
    __syncthreads();
#pragma unroll
    for (int t = 0; t < 4; ++t) {
        if (t < 3) stageA((t + 1) & 1, t + 1);
        computeT(t & 1, t);
        __syncthreads();
    }

#pragma unroll
    for (int mf = 0; mf < 2; ++mf)
#pragma unroll
        for (int nf = 0; nf < 2; ++nf)
#pragma unroll
            for (int r = 0; r < 4; ++r) {
                int grow = bm + wr_ * 32 + mf * 16 + l4 * 4 + r;
                int col = bn + wc_ * 32 + nf * 16 + l15;
                PQ[(size_t)grow * 1024 + col] = (bf16)acc[mf][nf][r];
            }
}

// ---------------------------------------------------------------------------
// Edge aggregation v5 (FIXED): Q-block (64x512 bf16 = 64 KB) staged in LDS
// via GLL with PER-LANE global source (+lane*8 elems = +16 B);
// inner loop is conflict-free ds_read_b32.
// Grid 1024: blk = b*16 + dgrp; 256 threads = 256 channel pairs, 4 dst each.
// Math identical to v4 (self term cancels exactly).
// ---------------------------------------------------------------------------
__global__ __launch_bounds__(256) void edge_agg_kernel(
    const bf16* __restrict__ PQ, const float* __restrict__ edges,
    const float* __restrict__ b1, bf16* __restrict__ S)
{
    __shared__ __align__(1024) char qs[65536];   // Qs[64][512] bf16
    __shared__ __align__(16) float wls[64][4];

    const int blk = blockIdx.x;
    const int dgrp = blk & 15;
    const int b = blk >> 4;
    const int tid = threadIdx.x;
    const int wave = tid >> 6, lane = tid & 63;
    const int d0 = dgrp * 4;

    const bf16* Pb = PQ + (size_t)(b * 64) * 1024;

    // stage Q rows: 64 rows x 1024 B; 16 GLL per wave; lane covers 16 B each
#pragma unroll
    for (int si = 0; si < 16; ++si) {
        int srcr = wave * 16 + si;
        GLL(Pb + (size_t)srcr * 1024 + 512 + lane * 8,
            qs + srcr * 1024 + lane * 16);
    }

    {
        int src = tid >> 2, dd = tid & 3;
        int d = d0 + dd;
        float w = 0.f;
        if (src != d) {
            int e = src * 63 + (d < src ? d : d - 1);
            float2 ev = ((const float2*)edges)[e];
            w = fmaxf(ev.x, ev.y);
        }
        wls[src][dd] = w;
    }

    f32x2 p2[4];
#pragma unroll
    for (int dd = 0; dd < 4; ++dd)
        p2[dd] = unpk(*(const unsigned int*)(Pb + (size_t)(d0 + dd) * 1024 + 2 * tid));
    float2 bbl = *(const float2*)(b1 + 2 * tid);
    f32x2 bb; bb.x = bbl.x; bb.y = bbl.y;

    __syncthreads();   // drains GLL (vmcnt) + orders wls

    const unsigned int* Qs32 = (const unsigned int*)qs;

    f32x2 acc[4];
#pragma unroll
    for (int dd = 0; dd < 4; ++dd) acc[dd] = (f32x2){0.f, 0.f};

#pragma unroll 4
    for (int src = 0; src < 64; ++src) {
        f32x2 q = unpk(Qs32[src * 256 + tid]);
        float4 wv = *(const float4*)&wls[src][0];
        float w[4] = {wv.x, wv.y, wv.z, wv.w};
#pragma unroll
        for (int dd = 0; dd < 4; ++dd) {
            f32x2 w2; w2.x = w[dd]; w2.y = w[dd];
            f32x2 v = (p2[dd] + q) * w2 + bb;
            float e0 = __expf(v.x) - 1.f;
            float e1 = __expf(v.y) - 1.f;
            f32x2 r;
            r.x = (v.x > 0.f) ? v.x : e0;
            r.y = (v.y > 0.f) ? v.y : e1;
            acc[dd] += r;
        }
    }
    f32x2 selfc;
    selfc.x = (bb.x > 0.f) ? bb.x : (__expf(bb.x) - 1.f);
    selfc.y = (bb.y > 0.f) ? bb.y : (__expf(bb.y) - 1.f);
#pragma unroll
    for (int dd = 0; dd < 4; ++dd) {
        bf16x2 st;
        st[0] = (bf16)(acc[dd].x - selfc.x);
        st[1] = (bf16)(acc[dd].y - selfc.y);
        *(bf16x2*)(S + (size_t)(b * 64 + d0 + dd) * 512 + 2 * tid) = st;
    }
}

// ---------------------------------------------------------------------------
// Small MFMA GEMM (R7 proven): tile 32x64, 4 waves (2x2) of 16x32, BK=64,
// dbuf, GLL. Grid (N/64, M/32) = 512 blocks -> 2 blocks/CU.
// MODE 1: Cb = bf16(A@B*scale + bias)
// MODE 2: Cb = bf16(relu(A@B + bias))
// MODE 3: 3 B-matrices + fused GRU -> Cf=NH fp32, Cb=NH bf16
// ---------------------------------------------------------------------------
template<int MODE>
__global__ __launch_bounds__(256) void small_gemm(
    const bf16* __restrict__ A, const bf16* __restrict__ Bt,
    const float* __restrict__ bias,
    float* __restrict__ Cf, bf16* __restrict__ Cb,
    int N, int K, float scale,
    const float* __restrict__ inputs, const float* __restrict__ hidden,
    const float* __restrict__ irw, const float* __restrict__ irb,
    const float* __restrict__ iiw, const float* __restrict__ iib,
    const float* __restrict__ inw, const float* __restrict__ inb)
{
    constexpr int NB  = (MODE == 3) ? 3 : 1;
    constexpr int ASZ = 32 * 64 * 2;
    constexpr int BSZ = 64 * 64 * 2 * NB;
    __shared__ __align__(1024) char smem[2 * (ASZ + BSZ)];

    const int tid  = threadIdx.x;
    const int wave = tid >> 6, lane = tid & 63;
    const int wr_  = wave >> 1, wc_ = wave & 1;
    const int l15  = lane & 15, l4 = lane >> 4;
    const int bm   = blockIdx.y * 32, bn = blockIdx.x * 64;

    const int srow = lane >> 3;
    const int scol = ((lane & 7) ^ (lane >> 3)) * 8;

    f32x4 acc[NB][2];
#pragma unroll
    for (int g = 0; g < NB; ++g)
#pragma unroll
        for (int nf = 0; nf < 2; ++nf)
            acc[g][nf] = (f32x4){0.f, 0.f, 0.f, 0.f};

    constexpr int per = (4 + 8 * NB) / 4;

    auto stage = [&](int buf, int kt) {
        char* base = smem + buf * (ASZ + BSZ);
#pragma unroll
        for (int si = 0; si < per; ++si) {
            int s = wave * per + si;
            char* ldst = base + s * 1024 + lane * 16;
            const bf16* g;
            if (s < 4) {
                g = A + ((size_t)(bm + s * 8 + srow) * K + kt * 64 + scol);
            } else {
                int sb = s - 4;
                int gi = sb >> 3, r8 = sb & 7;
                g = Bt + (size_t)gi * 256 * K
                      + (size_t)(bn + r8 * 8 + srow) * K + kt * 64 + scol;
            }
            GLL(g, ldst);
        }
    };

    auto compute = [&](int buf) {
        char* base = smem + buf * (ASZ + BSZ);
#pragma unroll
        for (int kk = 0; kk < 2; ++kk) {
            bf16x8 af = frag128(base, wr_ * 16 + l15, kk * 64 + l4 * 8);
#pragma unroll
            for (int g = 0; g < NB; ++g)
#pragma unroll
                for (int nf = 0; nf < 2; ++nf) {
                    bf16x8 bfr = frag128(base + ASZ + g * 8192,
                                         wc_ * 32 + nf * 16 + l15, kk * 64 + l4 * 8);
                    acc[g][nf] = MFMA(af, bfr, acc[g][nf]);
                }
        }
    };

    const int nt = K / 64;
    stage(0, 0);
    __syncthreads();
    for (int t = 0; t < nt; ++t) {
        if (t + 1 < nt) stage((t + 1) & 1, t + 1);
        compute(t & 1);
        __syncthreads();
    }

    if constexpr (MODE == 3) {
#pragma unroll
        for (int nf = 0; nf < 2; ++nf) {
            const int col = bn + wc_ * 32 + nf * 16 + l15;
            float w8r[8], w8i[8], w8n[8];
#pragma unroll
            for (int f = 0; f < 8; ++f) {
                w8r[f] = irw[f * 256 + col];
                w8i[f] = iiw[f * 256 + col];
                w8n[f] = inw[f * 256 + col];
            }
            const float xr0 = irb[col], xi0 = iib[col], xn0 = inb[col];
#pragma unroll
            for (int r = 0; r < 4; ++r) {
                const int grow = bm + wr_ * 16 + l4 * 4 + r;
                const float* inp = inputs + (size_t)grow * 8;
                float xr = xr0, xi = xi0, xn = xn0;
#pragma unroll
                for (int f = 0; f < 8; ++f) {
                    float x = inp[f];
                    xr += x * w8r[f]; xi += x * w8i[f]; xn += x * w8n[f];
                }
                float aR = acc[0][nf][r];
                float aI = acc[1][nf][r];
                float aN = acc[2][nf][r];
                float rg = __builtin_amdgcn_rcpf(1.f + __expf(-(xr + aR)));
                float ig = __builtin_amdgcn_rcpf(1.f + __expf(-(xi + aI)));
                float tz = xn + rg * aN;
                tz = fminf(fmaxf(tz, -15.f), 15.f);
                float e2x = __expf(2.f * tz);
                float nn = (e2x - 1.f) * __builtin_amdgcn_rcpf(e2x + 1.f);
                size_t o = (size_t)grow * 256 + col;
                float nh = (1.f - ig) * nn + ig * hidden[o];
                Cf[o] = nh;
                Cb[o] = (bf16)nh;
            }
        }
    } else {
#pragma unroll
        for (int nf = 0; nf < 2; ++nf)
#pragma unroll
            for (int r = 0; r < 4; ++r) {
                int grow = bm + wr_ * 16 + l4 * 4 + r;
                int col = bn + wc_ * 32 + nf * 16 + l15;
                float v = acc[0][nf][r];
                if constexpr (MODE == 1) v = v * scale + bias[col];
                if constexpr (MODE == 2) v = fmaxf(v + bias[col], 0.f);
                Cb[(size_t)grow * N + col] = (bf16)v;
            }
    }
}

// ---------------------------------------------------------------------------
// pred[row,f] = inputs[row,f] + H2[row,:] @ f3_w[:,f] + f3_b[f]
// ---------------------------------------------------------------------------
__global__ __launch_bounds__(256) void pred_kernel(
    const float* __restrict__ inputs, const bf16* __restrict__ H2,
    const float* __restrict__ f3_w, const float* __restrict__ f3_b,
    float* __restrict__ pred)
{
    __shared__ float f3s[2048];
    for (int i = threadIdx.x; i < 2048; i += 256) f3s[i] = f3_w[i];
    __syncthreads();

    const int idx = blockIdx.x * 256 + threadIdx.x;
    const int row = idx >> 3, f = idx & 7;
    const bf16* hr = H2 + (size_t)row * 256;
    float a = f3_b[f];
    for (int k0 = 0; k0 < 256; k0 += 8) {
        bf16x8 h8 = *(const bf16x8*)(hr + k0);
#pragma unroll
        for (int j = 0; j < 8; ++j)
            a += (float)h8[j] * f3s[(k0 + j) * 8 + f];
    }
    pred[idx] = inputs[idx] + a;
}

// ---------------------------------------------------------------------------
extern "C" void kernel_launch(void* const* d_in, const int* in_sizes, int n_in,
                              void* d_out, int out_size, void* d_ws, size_t ws_size,
                              hipStream_t stream) {
    const float* inputs = (const float*)d_in[0];
    const float* hidden = (const float*)d_in[1];
    const float* edges  = (const float*)d_in[2];
    const float* ed_w1 = (const float*)d_in[4];
    const float* ed_b1 = (const float*)d_in[5];
    const float* ed_w2 = (const float*)d_in[6];
    const float* ed_b2 = (const float*)d_in[7];
    const float* wr = (const float*)d_in[8];
    const float* wi = (const float*)d_in[9];
    const float* wh = (const float*)d_in[10];
    const float* ir_w = (const float*)d_in[11];
    const float* ir_b = (const float*)d_in[12];
    const float* ii_w = (const float*)d_in[13];
    const float* ii_b = (const float*)d_in[14];
    const float* in_w = (const float*)d_in[15];
    const float* in_b = (const float*)d_in[16];
    const float* f1_w = (const float*)d_in[17];
    const float* f1_b = (const float*)d_in[18];
    const float* f2_w = (const float*)d_in[19];
    const float* f2_b = (const float*)d_in[20];
    const float* f3_w = (const float*)d_in[21];
    const float* f3_b = (const float*)d_in[22];

    float* out = (float*)d_out;
    float* pred = out;
    float* NH = out + (size_t)BB * NN * FF;

    // bf16 workspace layout (element offsets)
    bf16* bws = (bf16*)d_ws;
    bf16* PQ   = bws;              // 4096*1024
    bf16* Sb   = bws + 4194304;    // 4096*512
    bf16* AGGb = bws + 6291456;    // 4096*256
    bf16* NHb  = bws + 7340032;    // 4096*256
    bf16* H1b  = bws + 8388608;    // 4096*256
    bf16* H2b  = bws + 9437184;    // 4096*256
    bf16* W2t  = bws + 10485760;   // 256*512
    bf16* Wg   = bws + 10616832;   // 3*256*256
    bf16* f1t  = bws + 10813440;   // 256*256
    bf16* f2t  = bws + 10878976;   // 256*256

    dim3 blk(256);

    // G1 (+pack as extra blocks): PQ = hidden @ [W1top|W1bot]
    g1pack_kernel<<<dim3(16, 71), blk, 0, stream>>>(
        hidden, ed_w1, ed_w2, wr, wi, wh, f1_w, f2_w,
        PQ, W2t, Wg, f1t, f2t);

    // S: per-(b,d) elu-sum over sources (Q staged in LDS)
    edge_agg_kernel<<<dim3(1024), blk, 0, stream>>>(PQ, edges, ed_b1, Sb);

    // G2: agg = S @ ed_w2 / 63 + ed_b2    (4096,256,512)
    small_gemm<1><<<dim3(4, 128), blk, 0, stream>>>(
        Sb, W2t, ed_b2, nullptr, AGGb, 256, 512, 1.f / 63.f,
        nullptr, nullptr, nullptr, nullptr, nullptr, nullptr, nullptr, nullptr);

    // G3: gates + fused GRU -> NH (fp32) + NHb (bf16)
    small_gemm<3><<<dim3(4, 128), blk, 0, stream>>>(
        AGGb, Wg, nullptr, NH, NHb, 256, 256, 1.f,
        inputs, hidden, ir_w, ir_b, ii_w, ii_b, in_w, in_b);

    // f1, f2 (relu)
    small_gemm<2><<<dim3(4, 128), blk, 0, stream>>>(
        NHb, f1t, f1_b, nullptr, H1b, 256, 256, 1.f,
        nullptr, nullptr, nullptr, nullptr, nullptr, nullptr, nullptr, nullptr);
    small_gemm<2><<<dim3(4, 128), blk, 0, stream>>>(
        H1b, f2t, f2_b, nullptr, H2b, 256, 256, 1.f,
        nullptr, nullptr, nullptr, nullptr, nullptr, nullptr, nullptr, nullptr);

    pred_kernel<<<dim3(128), blk, 0, stream>>>(inputs, H2b, f3_w, f3_b, pred);
}